// Round 1
// baseline (8006.984 us; speedup 1.0000x reference)
//
#include <hip/hip_runtime.h>
#include <math.h>

#define B_ 8
#define L_ 2048
#define DM 6
#define ED 48
#define NS 32
#define DCONV 16
#define NLAYERS 4
#define NCLASSES 4
#define EPS 1e-5f

// ---------------------------------------------------------------------------
// K1: RMSNorm over D_MODEL + in_proj (96 outputs per position).
// thread t -> (pos, o); redundant rms per 96 threads but trivially cheap.
__global__ void k_rms_inproj(const float* __restrict__ h,
                             const float* __restrict__ w,   // (96, 6) layer slice
                             const float* __restrict__ nw,  // (6) layer slice
                             float* __restrict__ xin, float* __restrict__ z)
{
    int t = blockIdx.x * blockDim.x + threadIdx.x;
    if (t >= B_ * L_ * 96) return;
    int pos = t / 96;
    int o   = t - pos * 96;
    const float* hp = h + pos * DM;
    float hv[DM];
    float ss = 0.f;
#pragma unroll
    for (int d = 0; d < DM; ++d) { hv[d] = hp[d]; ss += hv[d] * hv[d]; }
    float r = rsqrtf(ss * (1.0f / DM) + EPS);
    const float* wp = w + o * DM;
    float acc = 0.f;
#pragma unroll
    for (int d = 0; d < DM; ++d) acc += (hv[d] * r) * nw[d] * wp[d];
    if (o < ED) xin[pos * ED + o] = acc;
    else        z[pos * ED + (o - ED)] = acc;
}

// ---------------------------------------------------------------------------
// K2: causal depthwise conv (16 taps) + bias + SiLU
__global__ void k_conv_silu(const float* __restrict__ xin,
                            const float* __restrict__ cw,  // (48,16) layer slice
                            const float* __restrict__ cb,  // (48)
                            float* __restrict__ xc)
{
    int t = blockIdx.x * blockDim.x + threadIdx.x;
    if (t >= B_ * L_ * ED) return;
    int pos = t / ED;
    int e   = t - pos * ED;
    int l   = pos % L_;
    const float* wp = cw + e * DCONV;
    float acc = cb[e];
#pragma unroll
    for (int k = 0; k < DCONV; ++k) {
        int ll = l - (DCONV - 1) + k;
        if (ll >= 0)
            acc += xin[(pos - (DCONV - 1) + k) * ED + e] * wp[k];
    }
    xc[t] = acc / (1.f + expf(-acc));
}

// ---------------------------------------------------------------------------
// K3: x_proj: 65 outputs per position -> dr / B / C
__global__ void k_xproj(const float* __restrict__ xc,
                        const float* __restrict__ w,  // (65,48) layer slice
                        float* __restrict__ dr, float* __restrict__ Bm,
                        float* __restrict__ Cm)
{
    int t = blockIdx.x * blockDim.x + threadIdx.x;
    if (t >= B_ * L_ * 65) return;
    int pos = t / 65;
    int o   = t - pos * 65;
    const float* xp = xc + pos * ED;
    const float* wp = w + o * ED;
    float acc = 0.f;
#pragma unroll
    for (int e = 0; e < ED; ++e) acc += xp[e] * wp[e];
    if (o == 0)       dr[pos] = acc;
    else if (o <= NS) Bm[pos * NS + (o - 1)] = acc;
    else              Cm[pos * NS + (o - 1 - NS)] = acc;
}

// ---------------------------------------------------------------------------
// K3b: delta = softplus(dr * dt_w[e] + dt_b[e]) (stable form)
__global__ void k_delta(const float* __restrict__ dr,
                        const float* __restrict__ dtw,   // (48)
                        const float* __restrict__ dtb,   // (48)
                        float* __restrict__ delta)
{
    int t = blockIdx.x * blockDim.x + threadIdx.x;
    if (t >= B_ * L_ * ED) return;
    int pos = t / ED;
    int e   = t - pos * ED;
    float xv = dr[pos] * dtw[e] + dtb[e];
    delta[t] = fmaxf(xv, 0.f) + log1pf(expf(-fabsf(xv)));
}

// ---------------------------------------------------------------------------
// K4: selective scan. One 32-lane group per (b,e) chain; lane = state index n.
// Per step: h = exp(delta*A)*h + (delta*xc)*B; y = sum_n h*C + D*xc; gate.
__global__ void __launch_bounds__(256) k_scan(
    const float* __restrict__ delta, const float* __restrict__ xc,
    const float* __restrict__ Bm, const float* __restrict__ Cm,
    const float* __restrict__ z,
    const float* __restrict__ A_log,  // (48,32) layer slice
    const float* __restrict__ Dp,     // (48)
    float* __restrict__ y)
{
    int t = blockIdx.x * blockDim.x + threadIdx.x;
    int n   = t & 31;
    int grp = t >> 5;
    if (grp >= B_ * ED) return;
    int b = grp / ED;
    int e = grp - b * ED;
    float A  = -expf(A_log[e * NS + n]);
    float Dv = Dp[e];
    float h = 0.f;
    int posBase = b * L_;
    for (int l = 0; l < L_; ++l) {
        int pos = posBase + l;
        float dv = delta[pos * ED + e];
        float xv = xc[pos * ED + e];
        float bm = Bm[pos * NS + n];
        float cm = Cm[pos * NS + n];
        float dA = expf(dv * A);
        h = dA * h + (dv * xv) * bm;
        float p = h * cm;
#pragma unroll
        for (int off = 16; off > 0; off >>= 1)
            p += __shfl_xor(p, off, 32);
        if (n == 0) {
            float yr = p + Dv * xv;
            float zv = z[pos * ED + e];
            y[pos * ED + e] = yr * (zv / (1.f + expf(-zv)));
        }
    }
}

// ---------------------------------------------------------------------------
// K5: out_proj + residual (layers 0..2)
__global__ void k_outproj(const float* __restrict__ y,
                          const float* __restrict__ w,  // (6,48) layer slice
                          float* __restrict__ h)
{
    int t = blockIdx.x * blockDim.x + threadIdx.x;
    if (t >= B_ * L_ * DM) return;
    int pos = t / DM;
    int d   = t - pos * DM;
    const float* yp = y + pos * ED;
    const float* wp = w + d * ED;
    float acc = 0.f;
#pragma unroll
    for (int e = 0; e < ED; ++e) acc += yp[e] * wp[e];
    h[t] = acc + h[t];
}

// ---------------------------------------------------------------------------
// K6: classifier on last token of final layer's gated y
__global__ void k_cls(const float* __restrict__ y,
                      const float* __restrict__ fcw,  // (4,48)
                      const float* __restrict__ fcb,  // (4)
                      float* __restrict__ out)
{
    int t = threadIdx.x;
    if (t >= B_ * NCLASSES) return;
    int b = t / NCLASSES;
    int c = t - b * NCLASSES;
    const float* yp = y + (b * L_ + (L_ - 1)) * ED;
    const float* wp = fcw + c * ED;
    float acc = fcb[c];
#pragma unroll
    for (int e = 0; e < ED; ++e) acc += yp[e] * wp[e];
    out[t] = acc;
}

// ---------------------------------------------------------------------------
extern "C" void kernel_launch(void* const* d_in, const int* in_sizes, int n_in,
                              void* d_out, int out_size, void* d_ws, size_t ws_size,
                              hipStream_t stream)
{
    const float* x          = (const float*)d_in[0];
    const float* in_proj_w  = (const float*)d_in[1];
    const float* conv_w     = (const float*)d_in[2];
    const float* conv_b     = (const float*)d_in[3];
    const float* x_proj_w   = (const float*)d_in[4];
    const float* dt_proj_w  = (const float*)d_in[5];
    const float* dt_proj_b  = (const float*)d_in[6];
    const float* A_log      = (const float*)d_in[7];
    const float* Dp         = (const float*)d_in[8];
    const float* out_proj_w = (const float*)d_in[9];
    const float* norm_w     = (const float*)d_in[10];
    const float* fc_w       = (const float*)d_in[11];
    const float* fc_b       = (const float*)d_in[12];

    float* ws   = (float*)d_ws;
    float* h    = ws;                    // B*L*6     = 98304
    float* xin  = h    + B_ * L_ * DM;   // B*L*48    = 786432
    float* z    = xin  + B_ * L_ * ED;   // 786432
    float* xc   = z    + B_ * L_ * ED;   // 786432
    float* dr   = xc   + B_ * L_ * ED;   // B*L       = 16384
    float* Bmat = dr   + B_ * L_;        // B*L*32    = 524288
    float* Cmat = Bmat + B_ * L_ * NS;   // 524288
    float* delta= Cmat + B_ * L_ * NS;   // 786432
    float* y    = delta+ B_ * L_ * ED;   // 786432
    // total ~5.1M floats = 20.4 MB

    // h starts as x
    hipMemcpyAsync(h, x, (size_t)B_ * L_ * DM * sizeof(float),
                   hipMemcpyDeviceToDevice, stream);

    for (int i = 0; i < NLAYERS; ++i) {
        k_rms_inproj<<<(B_ * L_ * 96 + 255) / 256, 256, 0, stream>>>(
            h, in_proj_w + (size_t)i * 96 * DM, norm_w + (size_t)i * DM, xin, z);
        k_conv_silu<<<(B_ * L_ * ED + 255) / 256, 256, 0, stream>>>(
            xin, conv_w + (size_t)i * ED * DCONV, conv_b + (size_t)i * ED, xc);
        k_xproj<<<(B_ * L_ * 65 + 255) / 256, 256, 0, stream>>>(
            xc, x_proj_w + (size_t)i * 65 * ED, dr, Bmat, Cmat);
        k_delta<<<(B_ * L_ * ED + 255) / 256, 256, 0, stream>>>(
            dr, dt_proj_w + (size_t)i * ED, dt_proj_b + (size_t)i * ED, delta);
        k_scan<<<(B_ * ED * 32 + 255) / 256, 256, 0, stream>>>(
            delta, xc, Bmat, Cmat, z,
            A_log + (size_t)i * ED * NS, Dp + (size_t)i * ED, y);
        if (i < NLAYERS - 1)
            k_outproj<<<(B_ * L_ * DM + 255) / 256, 256, 0, stream>>>(
                y, out_proj_w + (size_t)i * DM * ED, h);
    }
    k_cls<<<1, 64, 0, stream>>>(y, fc_w, fc_b, (float*)d_out);
}

// Round 2
// 681.114 us; speedup vs baseline: 11.7557x; 11.7557x over previous
//
#include <hip/hip_runtime.h>
#include <math.h>

#define B_ 8
#define L_ 2048
#define DM 6
#define ED 48
#define NS 32
#define DCONV 16
#define NLAYERS 4
#define NCLASSES 4
#define EPS 1e-5f

#define CH 32              // chunks per chain
#define CL (L_ / CH)       // 64 steps per chunk

// ---------------------------------------------------------------------------
// K1: RMSNorm over D_MODEL + in_proj (96 outputs per position).
__global__ void k_rms_inproj(const float* __restrict__ h,
                             const float* __restrict__ w,   // (96, 6) layer slice
                             const float* __restrict__ nw,  // (6) layer slice
                             float* __restrict__ xin, float* __restrict__ z)
{
    int t = blockIdx.x * blockDim.x + threadIdx.x;
    if (t >= B_ * L_ * 96) return;
    int pos = t / 96;
    int o   = t - pos * 96;
    const float* hp = h + pos * DM;
    float hv[DM];
    float ss = 0.f;
#pragma unroll
    for (int d = 0; d < DM; ++d) { hv[d] = hp[d]; ss += hv[d] * hv[d]; }
    float r = rsqrtf(ss * (1.0f / DM) + EPS);
    const float* wp = w + o * DM;
    float acc = 0.f;
#pragma unroll
    for (int d = 0; d < DM; ++d) acc += (hv[d] * r) * nw[d] * wp[d];
    if (o < ED) xin[pos * ED + o] = acc;
    else        z[pos * ED + (o - ED)] = acc;
}

// ---------------------------------------------------------------------------
// K2: causal depthwise conv (16 taps) + bias + SiLU
__global__ void k_conv_silu(const float* __restrict__ xin,
                            const float* __restrict__ cw,  // (48,16) layer slice
                            const float* __restrict__ cb,  // (48)
                            float* __restrict__ xc)
{
    int t = blockIdx.x * blockDim.x + threadIdx.x;
    if (t >= B_ * L_ * ED) return;
    int pos = t / ED;
    int e   = t - pos * ED;
    int l   = pos % L_;
    const float* wp = cw + e * DCONV;
    float acc = cb[e];
#pragma unroll
    for (int k = 0; k < DCONV; ++k) {
        int ll = l - (DCONV - 1) + k;
        if (ll >= 0)
            acc += xin[(pos - (DCONV - 1) + k) * ED + e] * wp[k];
    }
    xc[t] = acc / (1.f + expf(-acc));
}

// ---------------------------------------------------------------------------
// K3: x_proj: 65 outputs per position -> dr / B / C
__global__ void k_xproj(const float* __restrict__ xc,
                        const float* __restrict__ w,  // (65,48) layer slice
                        float* __restrict__ dr, float* __restrict__ Bm,
                        float* __restrict__ Cm)
{
    int t = blockIdx.x * blockDim.x + threadIdx.x;
    if (t >= B_ * L_ * 65) return;
    int pos = t / 65;
    int o   = t - pos * 65;
    const float* xp = xc + pos * ED;
    const float* wp = w + o * ED;
    float acc = 0.f;
#pragma unroll
    for (int e = 0; e < ED; ++e) acc += xp[e] * wp[e];
    if (o == 0)       dr[pos] = acc;
    else if (o <= NS) Bm[pos * NS + (o - 1)] = acc;
    else              Cm[pos * NS + (o - 1 - NS)] = acc;
}

// ---------------------------------------------------------------------------
// K3b: delta = softplus(dr * dt_w[e] + dt_b[e]) (stable form)
__global__ void k_delta(const float* __restrict__ dr,
                        const float* __restrict__ dtw,   // (48)
                        const float* __restrict__ dtb,   // (48)
                        float* __restrict__ delta)
{
    int t = blockIdx.x * blockDim.x + threadIdx.x;
    if (t >= B_ * L_ * ED) return;
    int pos = t / ED;
    int e   = t - pos * ED;
    float xv = dr[pos] * dtw[e] + dtb[e];
    delta[t] = fmaxf(xv, 0.f) + log1pf(expf(-fabsf(xv)));
}

// ---------------------------------------------------------------------------
// Scan pass 1: per (b,e,n,chunk) local scan of CL steps from h=0.
// Stores chunk summary (prod of dA, local h end).
__global__ void __launch_bounds__(256) k_scan1(
    const float* __restrict__ delta, const float* __restrict__ xc,
    const float* __restrict__ Bm,
    const float* __restrict__ A_log,  // (48,32) layer slice
    float* __restrict__ sumA, float* __restrict__ sumH)
{
    int t = blockIdx.x * blockDim.x + threadIdx.x;
    int n = t & 31;
    int g = t >> 5;                 // (b*ED + e)*CH + chunk
    if (g >= B_ * ED * CH) return;
    int chunk = g % CH;
    int be    = g / CH;
    int e = be % ED;
    int b = be / ED;
    float A = -expf(A_log[e * NS + n]);
    float h = 0.f, ap = 1.f;
    int pos0 = b * L_ + chunk * CL;
#pragma unroll 4
    for (int i = 0; i < CL; ++i) {
        int pos = pos0 + i;
        float dv = delta[pos * ED + e];
        float xv = xc[pos * ED + e];
        float bm = Bm[pos * NS + n];
        float dA = expf(dv * A);
        h = dA * h + (dv * xv) * bm;
        ap *= dA;
    }
    sumA[g * NS + n] = ap;
    sumH[g * NS + n] = h;
}

// ---------------------------------------------------------------------------
// Scan pass 2: per (b,e,n), exclusive scan over the CH chunk summaries.
__global__ void k_scan2(const float* __restrict__ sumA,
                        const float* __restrict__ sumH,
                        float* __restrict__ hpre)
{
    int t = blockIdx.x * blockDim.x + threadIdx.x;
    if (t >= B_ * ED * NS) return;
    int n  = t & 31;
    int be = t >> 5;
    float p = 0.f;
#pragma unroll
    for (int c = 0; c < CH; ++c) {
        int idx = (be * CH + c) * NS + n;
        hpre[idx] = p;
        p = sumA[idx] * p + sumH[idx];
    }
}

// ---------------------------------------------------------------------------
// Scan pass 3: rescan each chunk from its prefix; reduce h*C over n (32 lanes);
// fuse D*x + SiLU(z) gate; write y.
__global__ void __launch_bounds__(256) k_scan3(
    const float* __restrict__ delta, const float* __restrict__ xc,
    const float* __restrict__ Bm, const float* __restrict__ Cm,
    const float* __restrict__ z,
    const float* __restrict__ A_log,  // (48,32) layer slice
    const float* __restrict__ Dp,     // (48)
    const float* __restrict__ hpre,
    float* __restrict__ y)
{
    int t = blockIdx.x * blockDim.x + threadIdx.x;
    int n = t & 31;
    int g = t >> 5;
    if (g >= B_ * ED * CH) return;
    int chunk = g % CH;
    int be    = g / CH;
    int e = be % ED;
    int b = be / ED;
    float A  = -expf(A_log[e * NS + n]);
    float Dv = Dp[e];
    float h  = hpre[g * NS + n];
    int pos0 = b * L_ + chunk * CL;
    for (int i = 0; i < CL; ++i) {
        int pos = pos0 + i;
        float dv = delta[pos * ED + e];
        float xv = xc[pos * ED + e];
        float bm = Bm[pos * NS + n];
        float cm = Cm[pos * NS + n];
        float dA = expf(dv * A);
        h = dA * h + (dv * xv) * bm;
        float p = h * cm;
#pragma unroll
        for (int off = 16; off > 0; off >>= 1)
            p += __shfl_xor(p, off, 32);
        if (n == 0) {
            float yr = p + Dv * xv;
            float zv = z[pos * ED + e];
            y[pos * ED + e] = yr * (zv / (1.f + expf(-zv)));
        }
    }
}

// ---------------------------------------------------------------------------
// K5: out_proj + residual (layers 0..2)
__global__ void k_outproj(const float* __restrict__ y,
                          const float* __restrict__ w,  // (6,48) layer slice
                          float* __restrict__ h)
{
    int t = blockIdx.x * blockDim.x + threadIdx.x;
    if (t >= B_ * L_ * DM) return;
    int pos = t / DM;
    int d   = t - pos * DM;
    const float* yp = y + pos * ED;
    const float* wp = w + d * ED;
    float acc = 0.f;
#pragma unroll
    for (int e = 0; e < ED; ++e) acc += yp[e] * wp[e];
    h[t] = acc + h[t];
}

// ---------------------------------------------------------------------------
// K6: classifier on last token of final layer's gated y
__global__ void k_cls(const float* __restrict__ y,
                      const float* __restrict__ fcw,  // (4,48)
                      const float* __restrict__ fcb,  // (4)
                      float* __restrict__ out)
{
    int t = threadIdx.x;
    if (t >= B_ * NCLASSES) return;
    int b = t / NCLASSES;
    int c = t - b * NCLASSES;
    const float* yp = y + (b * L_ + (L_ - 1)) * ED;
    const float* wp = fcw + c * ED;
    float acc = fcb[c];
#pragma unroll
    for (int e = 0; e < ED; ++e) acc += yp[e] * wp[e];
    out[t] = acc;
}

// ---------------------------------------------------------------------------
extern "C" void kernel_launch(void* const* d_in, const int* in_sizes, int n_in,
                              void* d_out, int out_size, void* d_ws, size_t ws_size,
                              hipStream_t stream)
{
    const float* x          = (const float*)d_in[0];
    const float* in_proj_w  = (const float*)d_in[1];
    const float* conv_w     = (const float*)d_in[2];
    const float* conv_b     = (const float*)d_in[3];
    const float* x_proj_w   = (const float*)d_in[4];
    const float* dt_proj_w  = (const float*)d_in[5];
    const float* dt_proj_b  = (const float*)d_in[6];
    const float* A_log      = (const float*)d_in[7];
    const float* Dp         = (const float*)d_in[8];
    const float* out_proj_w = (const float*)d_in[9];
    const float* norm_w     = (const float*)d_in[10];
    const float* fc_w       = (const float*)d_in[11];
    const float* fc_b       = (const float*)d_in[12];

    float* ws   = (float*)d_ws;
    float* h    = ws;                    // B*L*6     = 98304
    float* xin  = h    + B_ * L_ * DM;   // B*L*48    = 786432 (dead after conv)
    float* z    = xin  + B_ * L_ * ED;   // 786432
    float* xc   = z    + B_ * L_ * ED;   // 786432
    float* dr   = xc   + B_ * L_ * ED;   // B*L       = 16384
    float* Bmat = dr   + B_ * L_;        // B*L*32    = 524288
    float* Cmat = Bmat + B_ * L_ * NS;   // 524288
    float* delta= Cmat + B_ * L_ * NS;   // 786432
    float* y    = delta+ B_ * L_ * ED;   // 786432
    float* hpre = y    + B_ * L_ * ED;   // B*ED*CH*NS = 393216
    // scan chunk summaries reuse the dead xin buffer (2*393216 = 786432 fits)
    float* sumA = xin;
    float* sumH = xin + B_ * ED * CH * NS;

    hipMemcpyAsync(h, x, (size_t)B_ * L_ * DM * sizeof(float),
                   hipMemcpyDeviceToDevice, stream);

    const int nScanT = B_ * ED * CH * NS;   // 393216

    for (int i = 0; i < NLAYERS; ++i) {
        k_rms_inproj<<<(B_ * L_ * 96 + 255) / 256, 256, 0, stream>>>(
            h, in_proj_w + (size_t)i * 96 * DM, norm_w + (size_t)i * DM, xin, z);
        k_conv_silu<<<(B_ * L_ * ED + 255) / 256, 256, 0, stream>>>(
            xin, conv_w + (size_t)i * ED * DCONV, conv_b + (size_t)i * ED, xc);
        k_xproj<<<(B_ * L_ * 65 + 255) / 256, 256, 0, stream>>>(
            xc, x_proj_w + (size_t)i * 65 * ED, dr, Bmat, Cmat);
        k_delta<<<(B_ * L_ * ED + 255) / 256, 256, 0, stream>>>(
            dr, dt_proj_w + (size_t)i * ED, dt_proj_b + (size_t)i * ED, delta);
        k_scan1<<<(nScanT + 255) / 256, 256, 0, stream>>>(
            delta, xc, Bmat, A_log + (size_t)i * ED * NS, sumA, sumH);
        k_scan2<<<(B_ * ED * NS + 255) / 256, 256, 0, stream>>>(
            sumA, sumH, hpre);
        k_scan3<<<(nScanT + 255) / 256, 256, 0, stream>>>(
            delta, xc, Bmat, Cmat, z,
            A_log + (size_t)i * ED * NS, Dp + (size_t)i * ED, hpre, y);
        if (i < NLAYERS - 1)
            k_outproj<<<(B_ * L_ * DM + 255) / 256, 256, 0, stream>>>(
                y, out_proj_w + (size_t)i * DM * ED, h);
    }
    k_cls<<<1, 64, 0, stream>>>(y, fc_w, fc_b, (float*)d_out);
}

// Round 3
// 556.156 us; speedup vs baseline: 14.3970x; 1.2247x over previous
//
#include <hip/hip_runtime.h>
#include <math.h>

#define B_ 8
#define L_ 2048
#define DM 6
#define ED 48
#define NS 32
#define DCONV 16
#define NLAYERS 4
#define NCLASSES 4
#define EPS 1e-5f

#define CH 32              // chunks per chain
#define CL (L_ / CH)       // 64 steps per chunk

// All activations channel-major: [b][feat][l]  (l contiguous)

// ---------------------------------------------------------------------------
// K0: transpose input x [b][l][d] -> h [b][d][l]
__global__ void k_transpose_in(const float* __restrict__ x, float* __restrict__ h)
{
    int t = blockIdx.x * blockDim.x + threadIdx.x;
    if (t >= B_ * DM * L_) return;
    int l  = t % L_;
    int bd = t / L_;
    int d  = bd % DM;
    int b  = bd / DM;
    h[t] = x[(b * L_ + l) * DM + d];
}

// ---------------------------------------------------------------------------
// K1: RMSNorm + in_proj. thread t = o*(B*L) + b*L + l (o wave-uniform).
__global__ void k_rms_inproj(const float* __restrict__ h,
                             const float* __restrict__ w,   // (96,6)
                             const float* __restrict__ nw,  // (6)
                             float* __restrict__ xin, float* __restrict__ z)
{
    int t = blockIdx.x * blockDim.x + threadIdx.x;
    if (t >= 96 * B_ * L_) return;
    int o = t / (B_ * L_);
    int r = t - o * (B_ * L_);
    int b = r / L_;
    int l = r - b * L_;
    float hv[DM];
    float ss = 0.f;
#pragma unroll
    for (int d = 0; d < DM; ++d) {
        hv[d] = h[(b * DM + d) * L_ + l];
        ss += hv[d] * hv[d];
    }
    float rn = rsqrtf(ss * (1.0f / DM) + EPS);
    const float* wp = w + o * DM;
    float acc = 0.f;
#pragma unroll
    for (int d = 0; d < DM; ++d) acc += hv[d] * rn * nw[d] * wp[d];
    if (o < ED) xin[(b * ED + o) * L_ + l] = acc;
    else        z[(b * ED + (o - ED)) * L_ + l] = acc;
}

// ---------------------------------------------------------------------------
// K2: causal depthwise conv + bias + SiLU.  t linear over [b][e][l].
__global__ void k_conv_silu(const float* __restrict__ xin,
                            const float* __restrict__ cw,  // (48,16)
                            const float* __restrict__ cb,  // (48)
                            float* __restrict__ xc)
{
    int t = blockIdx.x * blockDim.x + threadIdx.x;
    if (t >= B_ * ED * L_) return;
    int l = t % L_;
    int e = (t / L_) % ED;
    int rowBase = t - l;
    const float* wp = cw + e * DCONV;
    float acc = cb[e];
#pragma unroll
    for (int k = 0; k < DCONV; ++k) {
        int ll = l - (DCONV - 1) + k;
        if (ll >= 0) acc += xin[rowBase + ll] * wp[k];
    }
    xc[t] = acc / (1.f + expf(-acc));
}

// ---------------------------------------------------------------------------
// K3: x_proj (65 outs) with delta fused into the o==0 waves.
// t = o*(B*L) + b*L + l  (o wave-uniform).
__global__ void k_xproj_delta(const float* __restrict__ xc,
                              const float* __restrict__ w,    // (65,48)
                              const float* __restrict__ dtw,  // (48)
                              const float* __restrict__ dtb,  // (48)
                              float* __restrict__ delta,
                              float* __restrict__ Bm, float* __restrict__ Cm)
{
    int t = blockIdx.x * blockDim.x + threadIdx.x;
    if (t >= 65 * B_ * L_) return;
    int o = t / (B_ * L_);
    int r = t - o * (B_ * L_);
    int b = r / L_;
    int l = r - b * L_;
    const float* xp = xc + (size_t)b * ED * L_ + l;   // stride L_ over e
    const float* wp = w + o * ED;
    float acc = 0.f;
#pragma unroll
    for (int e = 0; e < ED; ++e) acc += xp[e * L_] * wp[e];
    if (o == 0) {
        // delta[b][e][l] = softplus(acc*dtw[e] + dtb[e])
#pragma unroll 4
        for (int e = 0; e < ED; ++e) {
            float xv = acc * dtw[e] + dtb[e];
            delta[(b * ED + e) * L_ + l] =
                fmaxf(xv, 0.f) + log1pf(expf(-fabsf(xv)));
        }
    } else if (o <= NS) {
        Bm[(b * NS + (o - 1)) * L_ + l] = acc;
    } else {
        Cm[(b * NS + (o - 1 - NS)) * L_ + l] = acc;
    }
}

// ---------------------------------------------------------------------------
// Scan pass 1: per (b,e,n,chunk) local scan of CL steps from h=0, float4 steps.
__global__ void __launch_bounds__(256) k_scan1(
    const float* __restrict__ delta, const float* __restrict__ xc,
    const float* __restrict__ Bm,
    const float* __restrict__ A_log,  // (48,32)
    float* __restrict__ sumA, float* __restrict__ sumH)
{
    int t = blockIdx.x * blockDim.x + threadIdx.x;
    int n = t & 31;
    int g = t >> 5;                 // (b*ED+e)*CH + chunk
    if (g >= B_ * ED * CH) return;
    int chunk = g % CH;
    int be    = g / CH;
    int e = be % ED;
    int b = be / ED;
    float A = -expf(A_log[e * NS + n]);
    const float4* dRow = (const float4*)(delta + (size_t)(b * ED + e) * L_ + chunk * CL);
    const float4* xRow = (const float4*)(xc    + (size_t)(b * ED + e) * L_ + chunk * CL);
    const float4* bRow = (const float4*)(Bm    + (size_t)(b * NS + n) * L_ + chunk * CL);
    float h = 0.f, sd = 0.f;
#pragma unroll 4
    for (int q = 0; q < CL / 4; ++q) {
        float4 d4 = dRow[q];
        float4 x4 = xRow[q];
        float4 b4 = bRow[q];
        h = expf(d4.x * A) * h + (d4.x * x4.x) * b4.x;
        h = expf(d4.y * A) * h + (d4.y * x4.y) * b4.y;
        h = expf(d4.z * A) * h + (d4.z * x4.z) * b4.z;
        h = expf(d4.w * A) * h + (d4.w * x4.w) * b4.w;
        sd += d4.x + d4.y + d4.z + d4.w;
    }
    sumA[g * NS + n] = expf(A * sd);
    sumH[g * NS + n] = h;
}

// ---------------------------------------------------------------------------
// Scan pass 2: per (b,e,n), exclusive scan over CH chunk summaries.
__global__ void k_scan2(const float* __restrict__ sumA,
                        const float* __restrict__ sumH,
                        float* __restrict__ hpre)
{
    int t = blockIdx.x * blockDim.x + threadIdx.x;
    if (t >= B_ * ED * NS) return;
    int n  = t & 31;
    int be = t >> 5;
    float p = 0.f;
#pragma unroll
    for (int c = 0; c < CH; ++c) {
        int idx = (be * CH + c) * NS + n;
        hpre[idx] = p;
        p = sumA[idx] * p + sumH[idx];
    }
}

// ---------------------------------------------------------------------------
// Scan pass 3: rescan from prefix; batched 4-step multi-value reduce over n;
// lanes 0..3 of each 32-group apply D*x + SiLU(z) gate and write 4 contiguous y.
__global__ void __launch_bounds__(256) k_scan3(
    const float* __restrict__ delta, const float* __restrict__ xc,
    const float* __restrict__ Bm, const float* __restrict__ Cm,
    const float* __restrict__ z,
    const float* __restrict__ A_log,  // (48,32)
    const float* __restrict__ Dp,     // (48)
    const float* __restrict__ hpre,
    float* __restrict__ y)
{
    int t = blockIdx.x * blockDim.x + threadIdx.x;
    int n = t & 31;
    int g = t >> 5;
    if (g >= B_ * ED * CH) return;
    int chunk = g % CH;
    int be    = g / CH;
    int e = be % ED;
    int b = be / ED;
    float A  = -expf(A_log[e * NS + n]);
    float Dv = Dp[e];
    size_t eRow = (size_t)(b * ED + e) * L_ + chunk * CL;
    size_t nRow = (size_t)(b * NS + n) * L_ + chunk * CL;
    const float4* dRow = (const float4*)(delta + eRow);
    const float4* xRow = (const float4*)(xc + eRow);
    const float4* bRow = (const float4*)(Bm + nRow);
    const float4* cRow = (const float4*)(Cm + nRow);
    const float*  zRow = z + eRow;
    float*        yRow = y + eRow;
    float h = hpre[g * NS + n];
    int b0 = n & 1, b1 = n & 2;
    for (int q = 0; q < CL / 4; ++q) {
        float4 d4 = dRow[q];
        float4 x4 = xRow[q];
        float4 b4 = bRow[q];
        float4 c4 = cRow[q];
        h = expf(d4.x * A) * h + (d4.x * x4.x) * b4.x;  float p0 = h * c4.x;
        h = expf(d4.y * A) * h + (d4.y * x4.y) * b4.y;  float p1 = h * c4.y;
        h = expf(d4.z * A) * h + (d4.z * x4.z) * b4.z;  float p2 = h * c4.z;
        h = expf(d4.w * A) * h + (d4.w * x4.w) * b4.w;  float p3 = h * c4.w;
        // multi-value reduce: after this, lane%4==k holds sum over 32 lanes of p_k
        float u  = b0 ? p1 : p0;
        float us = b0 ? p0 : p1;
        u += __shfl_xor(us, 1, 32);
        float v  = b0 ? p3 : p2;
        float vs = b0 ? p2 : p3;
        v += __shfl_xor(vs, 1, 32);
        float wv  = b1 ? v : u;
        float wvs = b1 ? u : v;
        wv += __shfl_xor(wvs, 2, 32);
        wv += __shfl_xor(wv, 4, 32);
        wv += __shfl_xor(wv, 8, 32);
        wv += __shfl_xor(wv, 16, 32);
        if (n < 4) {
            int l4 = q * 4;
            float xs = (n == 0) ? x4.x : (n == 1) ? x4.y : (n == 2) ? x4.z : x4.w;
            float yr = wv + Dv * xs;
            float zv = zRow[l4 + n];
            yRow[l4 + n] = yr * (zv / (1.f + expf(-zv)));
        }
    }
}

// ---------------------------------------------------------------------------
// K5: out_proj + residual (layers 0..2). t linear over [b][d][l].
__global__ void k_outproj(const float* __restrict__ y,
                          const float* __restrict__ w,  // (6,48)
                          float* __restrict__ h)
{
    int t = blockIdx.x * blockDim.x + threadIdx.x;
    if (t >= B_ * DM * L_) return;
    int l = t % L_;
    int bd = t / L_;
    int d = bd % DM;
    int b = bd / DM;
    const float* yp = y + (size_t)b * ED * L_ + l;  // stride L_ over e
    const float* wp = w + d * ED;
    float acc = 0.f;
#pragma unroll
    for (int e = 0; e < ED; ++e) acc += yp[e * L_] * wp[e];
    h[t] = acc + h[t];
}

// ---------------------------------------------------------------------------
// K6: classifier on last token (y is already gated).
__global__ void k_cls(const float* __restrict__ y,
                      const float* __restrict__ fcw,  // (4,48)
                      const float* __restrict__ fcb,  // (4)
                      float* __restrict__ out)
{
    int t = threadIdx.x;
    if (t >= B_ * NCLASSES) return;
    int b = t / NCLASSES;
    int c = t - b * NCLASSES;
    const float* yp = y + (size_t)b * ED * L_ + (L_ - 1);
    const float* wp = fcw + c * ED;
    float acc = fcb[c];
#pragma unroll
    for (int e = 0; e < ED; ++e) acc += yp[e * L_] * wp[e];
    out[t] = acc;
}

// ---------------------------------------------------------------------------
extern "C" void kernel_launch(void* const* d_in, const int* in_sizes, int n_in,
                              void* d_out, int out_size, void* d_ws, size_t ws_size,
                              hipStream_t stream)
{
    const float* x          = (const float*)d_in[0];
    const float* in_proj_w  = (const float*)d_in[1];
    const float* conv_w     = (const float*)d_in[2];
    const float* conv_b     = (const float*)d_in[3];
    const float* x_proj_w   = (const float*)d_in[4];
    const float* dt_proj_w  = (const float*)d_in[5];
    const float* dt_proj_b  = (const float*)d_in[6];
    const float* A_log      = (const float*)d_in[7];
    const float* Dp         = (const float*)d_in[8];
    const float* out_proj_w = (const float*)d_in[9];
    const float* norm_w     = (const float*)d_in[10];
    const float* fc_w       = (const float*)d_in[11];
    const float* fc_b       = (const float*)d_in[12];

    float* ws   = (float*)d_ws;
    float* h    = ws;                    // B*6*L   = 98304   [b][d][l]
    float* xin  = h    + B_ * DM * L_;   // B*48*L  = 786432  [b][e][l]
    float* z    = xin  + B_ * ED * L_;   // 786432
    float* xc   = z    + B_ * ED * L_;   // 786432
    float* Bmat = xc   + B_ * ED * L_;   // B*32*L  = 524288  [b][n][l]
    float* Cmat = Bmat + B_ * NS * L_;   // 524288
    float* delta= Cmat + B_ * NS * L_;   // 786432  [b][e][l]
    float* y    = delta+ B_ * ED * L_;   // 786432  [b][e][l]
    float* hpre = y    + B_ * ED * L_;   // B*ED*CH*NS = 393216
    // chunk summaries reuse dead xin (786432 >= 2*393216)
    float* sumA = xin;
    float* sumH = xin + B_ * ED * CH * NS;

    const int nScanT = B_ * ED * CH * NS;   // 393216

    k_transpose_in<<<(B_ * DM * L_ + 255) / 256, 256, 0, stream>>>(x, h);

    for (int i = 0; i < NLAYERS; ++i) {
        k_rms_inproj<<<(96 * B_ * L_ + 255) / 256, 256, 0, stream>>>(
            h, in_proj_w + (size_t)i * 96 * DM, norm_w + (size_t)i * DM, xin, z);
        k_conv_silu<<<(B_ * ED * L_ + 255) / 256, 256, 0, stream>>>(
            xin, conv_w + (size_t)i * ED * DCONV, conv_b + (size_t)i * ED, xc);
        k_xproj_delta<<<(65 * B_ * L_ + 255) / 256, 256, 0, stream>>>(
            xc, x_proj_w + (size_t)i * 65 * ED,
            dt_proj_w + (size_t)i * ED, dt_proj_b + (size_t)i * ED,
            delta, Bmat, Cmat);
        k_scan1<<<(nScanT + 255) / 256, 256, 0, stream>>>(
            delta, xc, Bmat, A_log + (size_t)i * ED * NS, sumA, sumH);
        k_scan2<<<(B_ * ED * NS + 255) / 256, 256, 0, stream>>>(
            sumA, sumH, hpre);
        k_scan3<<<(nScanT + 255) / 256, 256, 0, stream>>>(
            delta, xc, Bmat, Cmat, z,
            A_log + (size_t)i * ED * NS, Dp + (size_t)i * ED, hpre, y);
        if (i < NLAYERS - 1)
            k_outproj<<<(B_ * DM * L_ + 255) / 256, 256, 0, stream>>>(
                y, out_proj_w + (size_t)i * DM * ED, h);
    }
    k_cls<<<1, 64, 0, stream>>>(y, fc_w, fc_b, (float*)d_out);
}

// Round 4
// 479.370 us; speedup vs baseline: 16.7031x; 1.1602x over previous
//
#include <hip/hip_runtime.h>
#include <math.h>

#define B_ 8
#define L_ 2048
#define DM 6
#define ED 48
#define NS 32
#define DCONV 16
#define NLAYERS 4
#define NCLASSES 4
#define EPS 1e-5f

#define CH 32              // chunks per chain
#define CL (L_ / CH)       // 64 steps per chunk

// Layouts:
//   h, xin, z, xc, delta, y : [b][feat][l]   (l contiguous)
//   Bm, Cm                  : [b][l][n]      (n contiguous)  <- scan-read optimal

// ---------------------------------------------------------------------------
// K0: transpose input x [b][l][d] -> h [b][d][l]
__global__ void k_transpose_in(const float* __restrict__ x, float* __restrict__ h)
{
    int t = blockIdx.x * blockDim.x + threadIdx.x;
    if (t >= B_ * DM * L_) return;
    int l  = t % L_;
    int bd = t / L_;
    int d  = bd % DM;
    int b  = bd / DM;
    h[t] = x[(b * L_ + l) * DM + d];
}

// ---------------------------------------------------------------------------
// K1: RMSNorm + in_proj. thread t = o*(B*L) + b*L + l (o wave-uniform).
__global__ void k_rms_inproj(const float* __restrict__ h,
                             const float* __restrict__ w,   // (96,6)
                             const float* __restrict__ nw,  // (6)
                             float* __restrict__ xin, float* __restrict__ z)
{
    int t = blockIdx.x * blockDim.x + threadIdx.x;
    if (t >= 96 * B_ * L_) return;
    int o = t / (B_ * L_);
    int r = t - o * (B_ * L_);
    int b = r / L_;
    int l = r - b * L_;
    float hv[DM];
    float ss = 0.f;
#pragma unroll
    for (int d = 0; d < DM; ++d) {
        hv[d] = h[(b * DM + d) * L_ + l];
        ss += hv[d] * hv[d];
    }
    float rn = rsqrtf(ss * (1.0f / DM) + EPS);
    const float* wp = w + o * DM;
    float acc = 0.f;
#pragma unroll
    for (int d = 0; d < DM; ++d) acc += hv[d] * rn * nw[d] * wp[d];
    if (o < ED) xin[(b * ED + o) * L_ + l] = acc;
    else        z[(b * ED + (o - ED)) * L_ + l] = acc;
}

// ---------------------------------------------------------------------------
// K2: causal depthwise conv + bias + SiLU.  t linear over [b][e][l].
__global__ void k_conv_silu(const float* __restrict__ xin,
                            const float* __restrict__ cw,  // (48,16)
                            const float* __restrict__ cb,  // (48)
                            float* __restrict__ xc)
{
    int t = blockIdx.x * blockDim.x + threadIdx.x;
    if (t >= B_ * ED * L_) return;
    int l = t % L_;
    int e = (t / L_) % ED;
    int rowBase = t - l;
    const float* wp = cw + e * DCONV;
    float acc = cb[e];
#pragma unroll
    for (int k = 0; k < DCONV; ++k) {
        int ll = l - (DCONV - 1) + k;
        if (ll >= 0) acc += xin[rowBase + ll] * wp[k];
    }
    xc[t] = acc / (1.f + __expf(-acc));
}

// ---------------------------------------------------------------------------
// K3: x_proj + delta, one thread per (b,l). xc cached in 48 VGPRs.
// Writes: delta [b][e][l] (lane-coalesced per e), Bm/Cm [b][l][n] (per-thread
// contiguous rows of 32).
__global__ void k_xproj_delta(const float* __restrict__ xc,
                              const float* __restrict__ w,    // (65,48)
                              const float* __restrict__ dtw,  // (48)
                              const float* __restrict__ dtb,  // (48)
                              float* __restrict__ delta,
                              float* __restrict__ Bm, float* __restrict__ Cm)
{
    int t = blockIdx.x * blockDim.x + threadIdx.x;
    if (t >= B_ * L_) return;
    int b = t / L_;
    int l = t - b * L_;
    float xv[ED];
#pragma unroll
    for (int e = 0; e < ED; ++e) xv[e] = xc[((size_t)b * ED + e) * L_ + l];

    // o == 0 -> dr -> delta over all 48 channels
    float dr = 0.f;
#pragma unroll
    for (int e = 0; e < ED; ++e) dr += xv[e] * w[e];
#pragma unroll 4
    for (int e = 0; e < ED; ++e) {
        float s = dr * dtw[e] + dtb[e];
        delta[((size_t)b * ED + e) * L_ + l] =
            fmaxf(s, 0.f) + log1pf(__expf(-fabsf(s)));
    }

    float* bOut = Bm + (size_t)t * NS;
    float* cOut = Cm + (size_t)t * NS;
#pragma unroll 4
    for (int n = 0; n < NS; ++n) {
        const float* wb = w + (1 + n) * ED;
        const float* wc = w + (1 + NS + n) * ED;
        float ab = 0.f, ac = 0.f;
#pragma unroll
        for (int e = 0; e < ED; ++e) {
            ab += xv[e] * wb[e];
            ac += xv[e] * wc[e];
        }
        bOut[n] = ab;
        cOut[n] = ac;
    }
}

// ---------------------------------------------------------------------------
// Scan pass 1: per (b,e,n,chunk) local scan of CL steps from h=0.
// B loads: one dword/step, coalesced across the 32-group (n contiguous).
__global__ void __launch_bounds__(256) k_scan1(
    const float* __restrict__ delta, const float* __restrict__ xc,
    const float* __restrict__ Bm,
    const float* __restrict__ A_log,  // (48,32)
    float* __restrict__ sumA, float* __restrict__ sumH)
{
    int t = blockIdx.x * blockDim.x + threadIdx.x;
    int n = t & 31;
    int g = t >> 5;                 // (b*ED+e)*CH + chunk
    if (g >= B_ * ED * CH) return;
    int chunk = g % CH;
    int be    = g / CH;
    int e = be % ED;
    int b = be / ED;
    float A = -__expf(A_log[e * NS + n]);
    size_t eRow = (size_t)(b * ED + e) * L_ + chunk * CL;
    const float4* dRow = (const float4*)(delta + eRow);
    const float4* xRow = (const float4*)(xc + eRow);
    const float* bBase = Bm + ((size_t)b * L_ + chunk * CL) * NS + n;
    float h = 0.f, sd = 0.f;
#pragma unroll 4
    for (int q = 0; q < CL / 4; ++q) {
        float4 d4 = dRow[q];
        float4 x4 = xRow[q];
        float b0 = bBase[(4 * q + 0) * NS];
        float b1 = bBase[(4 * q + 1) * NS];
        float b2 = bBase[(4 * q + 2) * NS];
        float b3 = bBase[(4 * q + 3) * NS];
        h = __expf(d4.x * A) * h + (d4.x * x4.x) * b0;
        h = __expf(d4.y * A) * h + (d4.y * x4.y) * b1;
        h = __expf(d4.z * A) * h + (d4.z * x4.z) * b2;
        h = __expf(d4.w * A) * h + (d4.w * x4.w) * b3;
        sd += d4.x + d4.y + d4.z + d4.w;
    }
    sumA[g * NS + n] = __expf(A * sd);
    sumH[g * NS + n] = h;
}

// ---------------------------------------------------------------------------
// Scan pass 2: per (b,e,n), exclusive scan over CH chunk summaries.
__global__ void k_scan2(const float* __restrict__ sumA,
                        const float* __restrict__ sumH,
                        float* __restrict__ hpre)
{
    int t = blockIdx.x * blockDim.x + threadIdx.x;
    if (t >= B_ * ED * NS) return;
    int n  = t & 31;
    int be = t >> 5;
    float p = 0.f;
#pragma unroll
    for (int c = 0; c < CH; ++c) {
        int idx = (be * CH + c) * NS + n;
        hpre[idx] = p;
        p = sumA[idx] * p + sumH[idx];
    }
}

// ---------------------------------------------------------------------------
// Scan pass 3: rescan from prefix; batched 4-step multi-value reduce over n;
// lanes 0..3 write 4 contiguous gated y.
__global__ void __launch_bounds__(256) k_scan3(
    const float* __restrict__ delta, const float* __restrict__ xc,
    const float* __restrict__ Bm, const float* __restrict__ Cm,
    const float* __restrict__ z,
    const float* __restrict__ A_log,  // (48,32)
    const float* __restrict__ Dp,     // (48)
    const float* __restrict__ hpre,
    float* __restrict__ y)
{
    int t = blockIdx.x * blockDim.x + threadIdx.x;
    int n = t & 31;
    int g = t >> 5;
    if (g >= B_ * ED * CH) return;
    int chunk = g % CH;
    int be    = g / CH;
    int e = be % ED;
    int b = be / ED;
    float A  = -__expf(A_log[e * NS + n]);
    float Dv = Dp[e];
    size_t eRow = (size_t)(b * ED + e) * L_ + chunk * CL;
    size_t nRow = ((size_t)b * L_ + chunk * CL) * NS + n;
    const float4* dRow = (const float4*)(delta + eRow);
    const float4* xRow = (const float4*)(xc + eRow);
    const float* bBase = Bm + nRow;
    const float* cBase = Cm + nRow;
    const float* zRow  = z + eRow;
    float*       yRow  = y + eRow;
    float h = hpre[g * NS + n];
    int s0 = n & 1, s1 = n & 2;
    for (int q = 0; q < CL / 4; ++q) {
        float4 d4 = dRow[q];
        float4 x4 = xRow[q];
        float bb0 = bBase[(4 * q + 0) * NS];
        float bb1 = bBase[(4 * q + 1) * NS];
        float bb2 = bBase[(4 * q + 2) * NS];
        float bb3 = bBase[(4 * q + 3) * NS];
        float cc0 = cBase[(4 * q + 0) * NS];
        float cc1 = cBase[(4 * q + 1) * NS];
        float cc2 = cBase[(4 * q + 2) * NS];
        float cc3 = cBase[(4 * q + 3) * NS];
        h = __expf(d4.x * A) * h + (d4.x * x4.x) * bb0;  float p0 = h * cc0;
        h = __expf(d4.y * A) * h + (d4.y * x4.y) * bb1;  float p1 = h * cc1;
        h = __expf(d4.z * A) * h + (d4.z * x4.z) * bb2;  float p2 = h * cc2;
        h = __expf(d4.w * A) * h + (d4.w * x4.w) * bb3;  float p3 = h * cc3;
        // multi-value butterfly: lane%4==k ends with sum over 32 lanes of p_k
        float u  = s0 ? p1 : p0;
        float us = s0 ? p0 : p1;
        u += __shfl_xor(us, 1, 32);
        float v  = s0 ? p3 : p2;
        float vs = s0 ? p2 : p3;
        v += __shfl_xor(vs, 1, 32);
        float wv  = s1 ? v : u;
        float wvs = s1 ? u : v;
        wv += __shfl_xor(wvs, 2, 32);
        wv += __shfl_xor(wv, 4, 32);
        wv += __shfl_xor(wv, 8, 32);
        wv += __shfl_xor(wv, 16, 32);
        if (n < 4) {
            int l4 = q * 4;
            float xs = (n == 0) ? x4.x : (n == 1) ? x4.y : (n == 2) ? x4.z : x4.w;
            float yr = wv + Dv * xs;
            float zv = zRow[l4 + n];
            yRow[l4 + n] = yr * (zv / (1.f + __expf(-zv)));
        }
    }
}

// ---------------------------------------------------------------------------
// K5: out_proj + residual (layers 0..2). t linear over [b][d][l].
__global__ void k_outproj(const float* __restrict__ y,
                          const float* __restrict__ w,  // (6,48)
                          float* __restrict__ h)
{
    int t = blockIdx.x * blockDim.x + threadIdx.x;
    if (t >= B_ * DM * L_) return;
    int l = t % L_;
    int bd = t / L_;
    int d = bd % DM;
    int b = bd / DM;
    const float* yp = y + (size_t)b * ED * L_ + l;  // stride L_ over e
    const float* wp = w + d * ED;
    float acc = 0.f;
#pragma unroll
    for (int e = 0; e < ED; ++e) acc += yp[e * L_] * wp[e];
    h[t] = acc + h[t];
}

// ---------------------------------------------------------------------------
// K6: classifier on last token (y is already gated).
__global__ void k_cls(const float* __restrict__ y,
                      const float* __restrict__ fcw,  // (4,48)
                      const float* __restrict__ fcb,  // (4)
                      float* __restrict__ out)
{
    int t = threadIdx.x;
    if (t >= B_ * NCLASSES) return;
    int b = t / NCLASSES;
    int c = t - b * NCLASSES;
    const float* yp = y + (size_t)b * ED * L_ + (L_ - 1);
    const float* wp = fcw + c * ED;
    float acc = fcb[c];
#pragma unroll
    for (int e = 0; e < ED; ++e) acc += yp[e * L_] * wp[e];
    out[t] = acc;
}

// ---------------------------------------------------------------------------
extern "C" void kernel_launch(void* const* d_in, const int* in_sizes, int n_in,
                              void* d_out, int out_size, void* d_ws, size_t ws_size,
                              hipStream_t stream)
{
    const float* x          = (const float*)d_in[0];
    const float* in_proj_w  = (const float*)d_in[1];
    const float* conv_w     = (const float*)d_in[2];
    const float* conv_b     = (const float*)d_in[3];
    const float* x_proj_w   = (const float*)d_in[4];
    const float* dt_proj_w  = (const float*)d_in[5];
    const float* dt_proj_b  = (const float*)d_in[6];
    const float* A_log      = (const float*)d_in[7];
    const float* Dp         = (const float*)d_in[8];
    const float* out_proj_w = (const float*)d_in[9];
    const float* norm_w     = (const float*)d_in[10];
    const float* fc_w       = (const float*)d_in[11];
    const float* fc_b       = (const float*)d_in[12];

    float* ws   = (float*)d_ws;
    float* h    = ws;                    // B*6*L   = 98304   [b][d][l]
    float* xin  = h    + B_ * DM * L_;   // B*48*L  = 786432  [b][e][l]
    float* z    = xin  + B_ * ED * L_;   // 786432
    float* xc   = z    + B_ * ED * L_;   // 786432
    float* Bmat = xc   + B_ * ED * L_;   // B*L*32  = 524288  [b][l][n]
    float* Cmat = Bmat + B_ * L_ * NS;   // 524288
    float* delta= Cmat + B_ * L_ * NS;   // 786432  [b][e][l]
    float* y    = delta+ B_ * ED * L_;   // 786432  [b][e][l]
    float* hpre = y    + B_ * ED * L_;   // B*ED*CH*NS = 393216
    // chunk summaries reuse dead xin (786432 >= 2*393216)
    float* sumA = xin;
    float* sumH = xin + B_ * ED * CH * NS;

    const int nScanT = B_ * ED * CH * NS;   // 393216

    k_transpose_in<<<(B_ * DM * L_ + 255) / 256, 256, 0, stream>>>(x, h);

    for (int i = 0; i < NLAYERS; ++i) {
        k_rms_inproj<<<(96 * B_ * L_ + 255) / 256, 256, 0, stream>>>(
            h, in_proj_w + (size_t)i * 96 * DM, norm_w + (size_t)i * DM, xin, z);
        k_conv_silu<<<(B_ * ED * L_ + 255) / 256, 256, 0, stream>>>(
            xin, conv_w + (size_t)i * ED * DCONV, conv_b + (size_t)i * ED, xc);
        k_xproj_delta<<<(B_ * L_ + 63) / 64, 64, 0, stream>>>(
            xc, x_proj_w + (size_t)i * 65 * ED,
            dt_proj_w + (size_t)i * ED, dt_proj_b + (size_t)i * ED,
            delta, Bmat, Cmat);
        k_scan1<<<(nScanT + 255) / 256, 256, 0, stream>>>(
            delta, xc, Bmat, A_log + (size_t)i * ED * NS, sumA, sumH);
        k_scan2<<<(B_ * ED * NS + 255) / 256, 256, 0, stream>>>(
            sumA, sumH, hpre);
        k_scan3<<<(nScanT + 255) / 256, 256, 0, stream>>>(
            delta, xc, Bmat, Cmat, z,
            A_log + (size_t)i * ED * NS, Dp + (size_t)i * ED, hpre, y);
        if (i < NLAYERS - 1)
            k_outproj<<<(B_ * DM * L_ + 255) / 256, 256, 0, stream>>>(
                y, out_proj_w + (size_t)i * DM * ED, h);
    }
    k_cls<<<1, 64, 0, stream>>>(y, fc_w, fc_b, (float*)d_out);
}

// Round 5
// 359.011 us; speedup vs baseline: 22.3029x; 1.3353x over previous
//
#include <hip/hip_runtime.h>
#include <math.h>

#define B_ 8
#define L_ 2048
#define DM 6
#define ED 48
#define NS 32
#define DCONV 16
#define NLAYERS 4
#define NCLASSES 4
#define EPS 1e-5f

#define CH 32              // chunks per chain
#define CL (L_ / CH)       // 64 steps per chunk

// Layouts:
//   h, xin, z, xc, delta, y : [b][feat][l]   (l contiguous)
//   Bm, Cm                  : [b][l][n]      (n contiguous)  <- scan-read optimal

// ---------------------------------------------------------------------------
// K0: transpose input x [b][l][d] -> h [b][d][l]
__global__ void k_transpose_in(const float* __restrict__ x, float* __restrict__ h)
{
    int t = blockIdx.x * blockDim.x + threadIdx.x;
    if (t >= B_ * DM * L_) return;
    int l  = t % L_;
    int bd = t / L_;
    int d  = bd % DM;
    int b  = bd / DM;
    h[t] = x[(b * L_ + l) * DM + d];
}

// ---------------------------------------------------------------------------
// K1: RMSNorm + in_proj. thread t = o*(B*L) + b*L + l (o wave-uniform).
__global__ void k_rms_inproj(const float* __restrict__ h,
                             const float* __restrict__ w,   // (96,6)
                             const float* __restrict__ nw,  // (6)
                             float* __restrict__ xin, float* __restrict__ z)
{
    int t = blockIdx.x * blockDim.x + threadIdx.x;
    if (t >= 96 * B_ * L_) return;
    int o = t / (B_ * L_);
    int r = t - o * (B_ * L_);
    int b = r / L_;
    int l = r - b * L_;
    float hv[DM];
    float ss = 0.f;
#pragma unroll
    for (int d = 0; d < DM; ++d) {
        hv[d] = h[(b * DM + d) * L_ + l];
        ss += hv[d] * hv[d];
    }
    float rn = rsqrtf(ss * (1.0f / DM) + EPS);
    const float* wp = w + o * DM;
    float acc = 0.f;
#pragma unroll
    for (int d = 0; d < DM; ++d) acc += hv[d] * rn * nw[d] * wp[d];
    if (o < ED) xin[(b * ED + o) * L_ + l] = acc;
    else        z[(b * ED + (o - ED)) * L_ + l] = acc;
}

// ---------------------------------------------------------------------------
// K2: causal depthwise conv + bias + SiLU.  t linear over [b][e][l].
__global__ void k_conv_silu(const float* __restrict__ xin,
                            const float* __restrict__ cw,  // (48,16)
                            const float* __restrict__ cb,  // (48)
                            float* __restrict__ xc)
{
    int t = blockIdx.x * blockDim.x + threadIdx.x;
    if (t >= B_ * ED * L_) return;
    int l = t % L_;
    int e = (t / L_) % ED;
    int rowBase = t - l;
    const float* wp = cw + e * DCONV;
    float acc = cb[e];
#pragma unroll
    for (int k = 0; k < DCONV; ++k) {
        int ll = l - (DCONV - 1) + k;
        if (ll >= 0) acc += xin[rowBase + ll] * wp[k];
    }
    xc[t] = acc / (1.f + __expf(-acc));
}

// ---------------------------------------------------------------------------
// K3: x_proj. Block = 32 positions x 8 output-groups (256 thr).
// Stage xc tile (48x32) in LDS; each thread computes 8 of the 64 B/C dots
// (weights wave-uniform -> scalar loads); dr computed by og==0 lanes.
// Writes Bm/Cm in [b][l][n] layout as two float4 per thread.
__global__ void __launch_bounds__(256) k_xproj(
    const float* __restrict__ xc,
    const float* __restrict__ w,    // (65,48)
    float* __restrict__ drb,
    float* __restrict__ Bm, float* __restrict__ Cm)
{
    __shared__ float xs[ED * 32];
    int b  = blockIdx.x >> 6;           // 2048/32 = 64 tiles per batch
    int l0 = (blockIdx.x & 63) * 32;
    int tid = threadIdx.x;
    for (int i = tid; i < ED * 32; i += 256) {
        int e = i >> 5, li = i & 31;
        xs[i] = xc[((size_t)b * ED + e) * L_ + l0 + li];
    }
    __syncthreads();
    int og = tid >> 5;                  // 0..7, wave-half-uniform
    int li = tid & 31;
    int isB = og < 4;
    int nb  = isB ? og * 8 : (og - 4) * 8;
    int rowBase = isB ? (1 + nb) : (1 + NS + nb);
    const float* wr = w + rowBase * ED;
    float acc0=0,acc1=0,acc2=0,acc3=0,acc4=0,acc5=0,acc6=0,acc7=0;
    float dr = 0.f;
#pragma unroll 4
    for (int e = 0; e < ED; ++e) {
        float xv = xs[e * 32 + li];
        acc0 += xv * wr[0 * ED + e];
        acc1 += xv * wr[1 * ED + e];
        acc2 += xv * wr[2 * ED + e];
        acc3 += xv * wr[3 * ED + e];
        acc4 += xv * wr[4 * ED + e];
        acc5 += xv * wr[5 * ED + e];
        acc6 += xv * wr[6 * ED + e];
        acc7 += xv * wr[7 * ED + e];
        dr   += xv * w[e];              // only og==0 keeps it
    }
    float* outp = (isB ? Bm : Cm) + ((size_t)(b * L_ + l0 + li)) * NS + nb;
    ((float4*)outp)[0] = make_float4(acc0, acc1, acc2, acc3);
    ((float4*)outp)[1] = make_float4(acc4, acc5, acc6, acc7);
    if (og == 0) drb[b * L_ + l0 + li] = dr;
}

// ---------------------------------------------------------------------------
// K3b: delta = softplus(dr * dtw[e] + dtb[e]), elementwise over [b][e][l].
__global__ void k_delta(const float* __restrict__ drb,
                        const float* __restrict__ dtw,
                        const float* __restrict__ dtb,
                        float* __restrict__ delta)
{
    int t = blockIdx.x * blockDim.x + threadIdx.x;
    if (t >= B_ * ED * L_) return;
    int l = t % L_;
    int e = (t / L_) % ED;
    int b = t / (ED * L_);
    float s = drb[b * L_ + l] * dtw[e] + dtb[e];
    delta[t] = fmaxf(s, 0.f) + log1pf(__expf(-fabsf(s)));
}

// ---------------------------------------------------------------------------
// Scan pass 1: per (b,e,n,chunk) local scan of CL steps from h=0.
__global__ void __launch_bounds__(256) k_scan1(
    const float* __restrict__ delta, const float* __restrict__ xc,
    const float* __restrict__ Bm,
    const float* __restrict__ A_log,  // (48,32)
    float* __restrict__ sumA, float* __restrict__ sumH)
{
    int t = blockIdx.x * blockDim.x + threadIdx.x;
    int n = t & 31;
    int g = t >> 5;                 // (b*ED+e)*CH + chunk
    if (g >= B_ * ED * CH) return;
    int chunk = g % CH;
    int be    = g / CH;
    int e = be % ED;
    int b = be / ED;
    float A = -__expf(A_log[e * NS + n]);
    size_t eRow = (size_t)(b * ED + e) * L_ + chunk * CL;
    const float4* dRow = (const float4*)(delta + eRow);
    const float4* xRow = (const float4*)(xc + eRow);
    const float* bBase = Bm + ((size_t)b * L_ + chunk * CL) * NS + n;
    float h = 0.f, sd = 0.f;
#pragma unroll 4
    for (int q = 0; q < CL / 4; ++q) {
        float4 d4 = dRow[q];
        float4 x4 = xRow[q];
        float b0 = bBase[(4 * q + 0) * NS];
        float b1 = bBase[(4 * q + 1) * NS];
        float b2 = bBase[(4 * q + 2) * NS];
        float b3 = bBase[(4 * q + 3) * NS];
        h = __expf(d4.x * A) * h + (d4.x * x4.x) * b0;
        h = __expf(d4.y * A) * h + (d4.y * x4.y) * b1;
        h = __expf(d4.z * A) * h + (d4.z * x4.z) * b2;
        h = __expf(d4.w * A) * h + (d4.w * x4.w) * b3;
        sd += d4.x + d4.y + d4.z + d4.w;
    }
    sumA[g * NS + n] = __expf(A * sd);
    sumH[g * NS + n] = h;
}

// ---------------------------------------------------------------------------
// Scan pass 2: per (b,e,n), exclusive scan over CH chunk summaries.
__global__ void k_scan2(const float* __restrict__ sumA,
                        const float* __restrict__ sumH,
                        float* __restrict__ hpre)
{
    int t = blockIdx.x * blockDim.x + threadIdx.x;
    if (t >= B_ * ED * NS) return;
    int n  = t & 31;
    int be = t >> 5;
    float p = 0.f;
#pragma unroll
    for (int c = 0; c < CH; ++c) {
        int idx = (be * CH + c) * NS + n;
        hpre[idx] = p;
        p = sumA[idx] * p + sumH[idx];
    }
}

// ---------------------------------------------------------------------------
// Scan pass 3: rescan from prefix; batched 4-step multi-value reduce over n;
// lanes 0..3 write 4 contiguous gated y.
__global__ void __launch_bounds__(256) k_scan3(
    const float* __restrict__ delta, const float* __restrict__ xc,
    const float* __restrict__ Bm, const float* __restrict__ Cm,
    const float* __restrict__ z,
    const float* __restrict__ A_log,  // (48,32)
    const float* __restrict__ Dp,     // (48)
    const float* __restrict__ hpre,
    float* __restrict__ y)
{
    int t = blockIdx.x * blockDim.x + threadIdx.x;
    int n = t & 31;
    int g = t >> 5;
    if (g >= B_ * ED * CH) return;
    int chunk = g % CH;
    int be    = g / CH;
    int e = be % ED;
    int b = be / ED;
    float A  = -__expf(A_log[e * NS + n]);
    float Dv = Dp[e];
    size_t eRow = (size_t)(b * ED + e) * L_ + chunk * CL;
    size_t nRow = ((size_t)b * L_ + chunk * CL) * NS + n;
    const float4* dRow = (const float4*)(delta + eRow);
    const float4* xRow = (const float4*)(xc + eRow);
    const float* bBase = Bm + nRow;
    const float* cBase = Cm + nRow;
    const float* zRow  = z + eRow;
    float*       yRow  = y + eRow;
    float h = hpre[g * NS + n];
    int s0 = n & 1, s1 = n & 2;
    for (int q = 0; q < CL / 4; ++q) {
        float4 d4 = dRow[q];
        float4 x4 = xRow[q];
        float bb0 = bBase[(4 * q + 0) * NS];
        float bb1 = bBase[(4 * q + 1) * NS];
        float bb2 = bBase[(4 * q + 2) * NS];
        float bb3 = bBase[(4 * q + 3) * NS];
        float cc0 = cBase[(4 * q + 0) * NS];
        float cc1 = cBase[(4 * q + 1) * NS];
        float cc2 = cBase[(4 * q + 2) * NS];
        float cc3 = cBase[(4 * q + 3) * NS];
        h = __expf(d4.x * A) * h + (d4.x * x4.x) * bb0;  float p0 = h * cc0;
        h = __expf(d4.y * A) * h + (d4.y * x4.y) * bb1;  float p1 = h * cc1;
        h = __expf(d4.z * A) * h + (d4.z * x4.z) * bb2;  float p2 = h * cc2;
        h = __expf(d4.w * A) * h + (d4.w * x4.w) * bb3;  float p3 = h * cc3;
        // multi-value butterfly: lane%4==k ends with sum over 32 lanes of p_k
        float u  = s0 ? p1 : p0;
        float us = s0 ? p0 : p1;
        u += __shfl_xor(us, 1, 32);
        float v  = s0 ? p3 : p2;
        float vs = s0 ? p2 : p3;
        v += __shfl_xor(vs, 1, 32);
        float wv  = s1 ? v : u;
        float wvs = s1 ? u : v;
        wv += __shfl_xor(wvs, 2, 32);
        wv += __shfl_xor(wv, 4, 32);
        wv += __shfl_xor(wv, 8, 32);
        wv += __shfl_xor(wv, 16, 32);
        if (n < 4) {
            int l4 = q * 4;
            float xs = (n == 0) ? x4.x : (n == 1) ? x4.y : (n == 2) ? x4.z : x4.w;
            float yr = wv + Dv * xs;
            float zv = zRow[l4 + n];
            yRow[l4 + n] = yr * (zv / (1.f + __expf(-zv)));
        }
    }
}

// ---------------------------------------------------------------------------
// K5: out_proj + residual (layers 0..2). t linear over [b][d][l].
__global__ void k_outproj(const float* __restrict__ y,
                          const float* __restrict__ w,  // (6,48)
                          float* __restrict__ h)
{
    int t = blockIdx.x * blockDim.x + threadIdx.x;
    if (t >= B_ * DM * L_) return;
    int l = t % L_;
    int bd = t / L_;
    int d = bd % DM;
    int b = bd / DM;
    const float* yp = y + (size_t)b * ED * L_ + l;  // stride L_ over e
    const float* wp = w + d * ED;
    float acc = 0.f;
#pragma unroll
    for (int e = 0; e < ED; ++e) acc += yp[e * L_] * wp[e];
    h[t] = acc + h[t];
}

// ---------------------------------------------------------------------------
// K6: classifier on last token (y is already gated).
__global__ void k_cls(const float* __restrict__ y,
                      const float* __restrict__ fcw,  // (4,48)
                      const float* __restrict__ fcb,  // (4)
                      float* __restrict__ out)
{
    int t = threadIdx.x;
    if (t >= B_ * NCLASSES) return;
    int b = t / NCLASSES;
    int c = t - b * NCLASSES;
    const float* yp = y + (size_t)b * ED * L_ + (L_ - 1);
    const float* wp = fcw + c * ED;
    float acc = fcb[c];
#pragma unroll
    for (int e = 0; e < ED; ++e) acc += yp[e * L_] * wp[e];
    out[t] = acc;
}

// ---------------------------------------------------------------------------
extern "C" void kernel_launch(void* const* d_in, const int* in_sizes, int n_in,
                              void* d_out, int out_size, void* d_ws, size_t ws_size,
                              hipStream_t stream)
{
    const float* x          = (const float*)d_in[0];
    const float* in_proj_w  = (const float*)d_in[1];
    const float* conv_w     = (const float*)d_in[2];
    const float* conv_b     = (const float*)d_in[3];
    const float* x_proj_w   = (const float*)d_in[4];
    const float* dt_proj_w  = (const float*)d_in[5];
    const float* dt_proj_b  = (const float*)d_in[6];
    const float* A_log      = (const float*)d_in[7];
    const float* Dp         = (const float*)d_in[8];
    const float* out_proj_w = (const float*)d_in[9];
    const float* norm_w     = (const float*)d_in[10];
    const float* fc_w       = (const float*)d_in[11];
    const float* fc_b       = (const float*)d_in[12];

    float* ws   = (float*)d_ws;
    float* h    = ws;                    // B*6*L   = 98304   [b][d][l]
    float* xin  = h    + B_ * DM * L_;   // B*48*L  = 786432  [b][e][l]
    float* z    = xin  + B_ * ED * L_;   // 786432
    float* xc   = z    + B_ * ED * L_;   // 786432
    float* Bmat = xc   + B_ * ED * L_;   // B*L*32  = 524288  [b][l][n]
    float* Cmat = Bmat + B_ * L_ * NS;   // 524288
    float* delta= Cmat + B_ * L_ * NS;   // 786432  [b][e][l]
    float* y    = delta+ B_ * ED * L_;   // 786432  [b][e][l]
    float* hpre = y    + B_ * ED * L_;   // B*ED*CH*NS = 393216
    float* drb  = hpre + B_ * ED * CH * NS;  // B*L = 16384
    // chunk summaries reuse dead xin (786432 >= 2*393216)
    float* sumA = xin;
    float* sumH = xin + B_ * ED * CH * NS;

    const int nScanT = B_ * ED * CH * NS;   // 393216

    k_transpose_in<<<(B_ * DM * L_ + 255) / 256, 256, 0, stream>>>(x, h);

    for (int i = 0; i < NLAYERS; ++i) {
        k_rms_inproj<<<(96 * B_ * L_ + 255) / 256, 256, 0, stream>>>(
            h, in_proj_w + (size_t)i * 96 * DM, norm_w + (size_t)i * DM, xin, z);
        k_conv_silu<<<(B_ * ED * L_ + 255) / 256, 256, 0, stream>>>(
            xin, conv_w + (size_t)i * ED * DCONV, conv_b + (size_t)i * ED, xc);
        k_xproj<<<B_ * (L_ / 32), 256, 0, stream>>>(
            xc, x_proj_w + (size_t)i * 65 * ED, drb, Bmat, Cmat);
        k_delta<<<(B_ * ED * L_ + 255) / 256, 256, 0, stream>>>(
            drb, dt_proj_w + (size_t)i * ED, dt_proj_b + (size_t)i * ED, delta);
        k_scan1<<<(nScanT + 255) / 256, 256, 0, stream>>>(
            delta, xc, Bmat, A_log + (size_t)i * ED * NS, sumA, sumH);
        k_scan2<<<(B_ * ED * NS + 255) / 256, 256, 0, stream>>>(
            sumA, sumH, hpre);
        k_scan3<<<(nScanT + 255) / 256, 256, 0, stream>>>(
            delta, xc, Bmat, Cmat, z,
            A_log + (size_t)i * ED * NS, Dp + (size_t)i * ED, hpre, y);
        if (i < NLAYERS - 1)
            k_outproj<<<(B_ * DM * L_ + 255) / 256, 256, 0, stream>>>(
                y, out_proj_w + (size_t)i * DM * ED, h);
    }
    k_cls<<<1, 64, 0, stream>>>(y, fc_w, fc_b, (float*)d_out);
}

// Round 6
// 341.543 us; speedup vs baseline: 23.4435x; 1.0511x over previous
//
#include <hip/hip_runtime.h>
#include <math.h>

#define B_ 8
#define L_ 2048
#define DM 6
#define ED 48
#define NS 32
#define DCONV 16
#define NLAYERS 4
#define NCLASSES 4
#define EPS 1e-5f

#define CH 32              // chunks per chain
#define CL (L_ / CH)       // 64 steps per chunk

// Layouts:
//   h, z, xc, delta, y : [b][feat][l]   (l contiguous)
//   Bm, Cm             : [b][l][n]      (n contiguous)  <- scan-read optimal

// ---------------------------------------------------------------------------
// Fused pre-scan kernel. Block = (b, 32-position tile of l).
// Does: residual update (y_prev @ outW^T + h_prev) with 15-pos halo,
// RMSNorm, in_proj (xin into LDS incl halo, z to global), causal conv+SiLU
// (xc to LDS+global), x_proj (B/C to global), softplus delta (to global).
__global__ void __launch_bounds__(256) k_fused_pre(
    const float* __restrict__ x,      // [b][l][dm] raw input (layer 0 only)
    const float* __restrict__ yprev,  // [b][e][l] gated y of prev layer
    const float* __restrict__ outw,   // (6,48) prev layer out_proj
    const float* __restrict__ hin,    // [b][dm][l] residual in (layer>0)
    float* __restrict__ hout,         // [b][dm][l] residual out
    const float* __restrict__ ipw,    // (96,6)
    const float* __restrict__ nw,     // (6)
    const float* __restrict__ cw,     // (48,16)
    const float* __restrict__ cb,     // (48)
    const float* __restrict__ xpw,    // (65,48)
    const float* __restrict__ dtw,    // (48)
    const float* __restrict__ dtb,    // (48)
    float* __restrict__ z,
    float* __restrict__ xcg,
    float* __restrict__ delta,
    float* __restrict__ Bm, float* __restrict__ Cm,
    int layer)
{
    __shared__ float sh[DM][48];     // residual h, 47 positions (l0-15..l0+31)
    __shared__ float sxin[ED][48];   // xin, 47 positions
    __shared__ float sxc[ED][33];    // xc, 32 positions (+1 pad)
    __shared__ float srn[48];        // rms scale per position
    __shared__ float sdr[32];        // dt-rank scalar per position

    int b  = blockIdx.x >> 6;            // 64 tiles per batch
    int l0 = (blockIdx.x & 63) * 32;
    int tid = threadIdx.x;

    // Phase 1: residual h for 47 positions
    for (int i = tid; i < DM * 47; i += 256) {
        int d = i / 47;
        int p = i % 47;
        int l = l0 - 15 + p;
        float hv = 0.f;
        if (l >= 0) {
            if (layer == 0) {
                hv = x[((size_t)b * L_ + l) * DM + d];
            } else {
                hv = hin[((size_t)b * DM + d) * L_ + l];
                const float* yp = yprev + (size_t)b * ED * L_ + l;
                const float* wp = outw + d * ED;
                float acc = 0.f;
#pragma unroll
                for (int e = 0; e < ED; ++e) acc += yp[(size_t)e * L_] * wp[e];
                hv += acc;
            }
            if (p >= 15 && layer < NLAYERS - 1)
                hout[((size_t)b * DM + d) * L_ + l] = hv;
        }
        sh[d][p] = hv;
    }
    __syncthreads();

    // Phase 2: rms scale per position
    if (tid < 47) {
        float ss = 0.f;
#pragma unroll
        for (int d = 0; d < DM; ++d) ss += sh[d][tid] * sh[d][tid];
        srn[tid] = rsqrtf(ss * (1.f / DM) + EPS);
    }
    __syncthreads();

    // Phase 3a: xin (47 positions, into LDS)
    for (int i = tid; i < ED * 47; i += 256) {
        int e = i / 47, p = i % 47;
        const float* wp = ipw + e * DM;
        float acc = 0.f;
#pragma unroll
        for (int d = 0; d < DM; ++d) acc += sh[d][p] * nw[d] * wp[d];
        sxin[e][p] = acc * srn[p];
    }
    // Phase 3b: z (32 owned positions, to global)
    for (int i = tid; i < ED * 32; i += 256) {
        int e = i >> 5, po = i & 31;
        int p = po + 15;
        const float* wp = ipw + (ED + e) * DM;
        float acc = 0.f;
#pragma unroll
        for (int d = 0; d < DM; ++d) acc += sh[d][p] * nw[d] * wp[d];
        z[((size_t)b * ED + e) * L_ + l0 + po] = acc * srn[p];
    }
    __syncthreads();

    // Phase 4: conv + SiLU (output position po -> tile index po+15)
    for (int i = tid; i < ED * 32; i += 256) {
        int e = i >> 5, po = i & 31;
        const float* wp = cw + e * DCONV;
        float acc = cb[e];
#pragma unroll
        for (int k = 0; k < DCONV; ++k) acc += sxin[e][po + k] * wp[k];
        float v = acc / (1.f + __expf(-acc));
        sxc[e][po] = v;
        xcg[((size_t)b * ED + e) * L_ + l0 + po] = v;
    }
    __syncthreads();

    // Phase 5: x_proj. og = 8 output-groups of 8 rows; li = position.
    {
        int og = tid >> 5, li = tid & 31;
        int isB = og < 4;
        int nb = isB ? og * 8 : (og - 4) * 8;
        int rowBase = isB ? (1 + nb) : (1 + NS + nb);
        const float* wr = xpw + rowBase * ED;
        float a0=0,a1=0,a2=0,a3=0,a4=0,a5=0,a6=0,a7=0, dr=0;
#pragma unroll 4
        for (int e = 0; e < ED; ++e) {
            float xv = sxc[e][li];
            a0 += xv * wr[0*ED+e]; a1 += xv * wr[1*ED+e];
            a2 += xv * wr[2*ED+e]; a3 += xv * wr[3*ED+e];
            a4 += xv * wr[4*ED+e]; a5 += xv * wr[5*ED+e];
            a6 += xv * wr[6*ED+e]; a7 += xv * wr[7*ED+e];
            dr += xv * xpw[e];
        }
        float* outp = (isB ? Bm : Cm) + ((size_t)(b * L_ + l0 + li)) * NS + nb;
        ((float4*)outp)[0] = make_float4(a0, a1, a2, a3);
        ((float4*)outp)[1] = make_float4(a4, a5, a6, a7);
        if (og == 0) sdr[li] = dr;
    }
    __syncthreads();

    // Phase 6: delta = softplus(dr*dtw + dtb)
    for (int i = tid; i < ED * 32; i += 256) {
        int e = i >> 5, po = i & 31;
        float s = sdr[po] * dtw[e] + dtb[e];
        delta[((size_t)b * ED + e) * L_ + l0 + po] =
            fmaxf(s, 0.f) + log1pf(__expf(-fabsf(s)));
    }
}

// ---------------------------------------------------------------------------
// Scan pass 1: per (b,e,n,chunk) local scan of CL steps from h=0.
// Writes chunk summary (telescoped exp(A*sum d), local h end).
__global__ void __launch_bounds__(256) k_scan1(
    const float* __restrict__ delta, const float* __restrict__ xc,
    const float* __restrict__ Bm,
    const float* __restrict__ A_log,  // (48,32)
    float* __restrict__ sumA, float* __restrict__ sumH)
{
    int t = blockIdx.x * blockDim.x + threadIdx.x;
    int n = t & 31;
    int g = t >> 5;                 // (b*ED+e)*CH + chunk
    if (g >= B_ * ED * CH) return;
    int chunk = g % CH;
    int be    = g / CH;
    int e = be % ED;
    int b = be / ED;
    float A = -__expf(A_log[e * NS + n]);
    size_t eRow = (size_t)(b * ED + e) * L_ + chunk * CL;
    const float4* dRow = (const float4*)(delta + eRow);
    const float4* xRow = (const float4*)(xc + eRow);
    const float* bBase = Bm + ((size_t)b * L_ + chunk * CL) * NS + n;
    float h = 0.f, sd = 0.f;
#pragma unroll 4
    for (int q = 0; q < CL / 4; ++q) {
        float4 d4 = dRow[q];
        float4 x4 = xRow[q];
        float b0 = bBase[(4 * q + 0) * NS];
        float b1 = bBase[(4 * q + 1) * NS];
        float b2 = bBase[(4 * q + 2) * NS];
        float b3 = bBase[(4 * q + 3) * NS];
        h = __expf(d4.x * A) * h + (d4.x * x4.x) * b0;
        h = __expf(d4.y * A) * h + (d4.y * x4.y) * b1;
        h = __expf(d4.z * A) * h + (d4.z * x4.z) * b2;
        h = __expf(d4.w * A) * h + (d4.w * x4.w) * b3;
        sd += d4.x + d4.y + d4.z + d4.w;
    }
    sumA[g * NS + n] = __expf(A * sd);
    sumH[g * NS + n] = h;
}

// ---------------------------------------------------------------------------
// Scan pass 3 (pass 2 inlined): each 32-group folds the chunk summaries
// before its own chunk to get its h prefix, then rescans; batched 4-step
// multi-value reduce over n; lanes 0..3 write 4 contiguous gated y.
__global__ void __launch_bounds__(256) k_scan3(
    const float* __restrict__ delta, const float* __restrict__ xc,
    const float* __restrict__ Bm, const float* __restrict__ Cm,
    const float* __restrict__ z,
    const float* __restrict__ A_log,  // (48,32)
    const float* __restrict__ Dp,     // (48)
    const float* __restrict__ sumA, const float* __restrict__ sumH,
    float* __restrict__ y)
{
    int t = blockIdx.x * blockDim.x + threadIdx.x;
    int n = t & 31;
    int g = t >> 5;
    if (g >= B_ * ED * CH) return;
    int chunk = g % CH;
    int be    = g / CH;
    int e = be % ED;
    int b = be / ED;
    float A  = -__expf(A_log[e * NS + n]);
    float Dv = Dp[e];

    // inline exclusive prefix over this chain's earlier chunk summaries
    float h = 0.f;
    int base = be * CH;
    for (int c = 0; c < chunk; ++c) {
        int idx = (base + c) * NS + n;
        h = sumA[idx] * h + sumH[idx];
    }

    size_t eRow = (size_t)(b * ED + e) * L_ + chunk * CL;
    size_t nRow = ((size_t)b * L_ + chunk * CL) * NS + n;
    const float4* dRow = (const float4*)(delta + eRow);
    const float4* xRow = (const float4*)(xc + eRow);
    const float* bBase = Bm + nRow;
    const float* cBase = Cm + nRow;
    const float* zRow  = z + eRow;
    float*       yRow  = y + eRow;
    int s0 = n & 1, s1 = n & 2;
    for (int q = 0; q < CL / 4; ++q) {
        float4 d4 = dRow[q];
        float4 x4 = xRow[q];
        float bb0 = bBase[(4 * q + 0) * NS];
        float bb1 = bBase[(4 * q + 1) * NS];
        float bb2 = bBase[(4 * q + 2) * NS];
        float bb3 = bBase[(4 * q + 3) * NS];
        float cc0 = cBase[(4 * q + 0) * NS];
        float cc1 = cBase[(4 * q + 1) * NS];
        float cc2 = cBase[(4 * q + 2) * NS];
        float cc3 = cBase[(4 * q + 3) * NS];
        h = __expf(d4.x * A) * h + (d4.x * x4.x) * bb0;  float p0 = h * cc0;
        h = __expf(d4.y * A) * h + (d4.y * x4.y) * bb1;  float p1 = h * cc1;
        h = __expf(d4.z * A) * h + (d4.z * x4.z) * bb2;  float p2 = h * cc2;
        h = __expf(d4.w * A) * h + (d4.w * x4.w) * bb3;  float p3 = h * cc3;
        // multi-value butterfly: lane%4==k ends with sum over 32 lanes of p_k
        float u  = s0 ? p1 : p0;
        float us = s0 ? p0 : p1;
        u += __shfl_xor(us, 1, 32);
        float v  = s0 ? p3 : p2;
        float vs = s0 ? p2 : p3;
        v += __shfl_xor(vs, 1, 32);
        float wv  = s1 ? v : u;
        float wvs = s1 ? u : v;
        wv += __shfl_xor(wvs, 2, 32);
        wv += __shfl_xor(wv, 4, 32);
        wv += __shfl_xor(wv, 8, 32);
        wv += __shfl_xor(wv, 16, 32);
        if (n < 4) {
            int l4 = q * 4;
            float xs = (n == 0) ? x4.x : (n == 1) ? x4.y : (n == 2) ? x4.z : x4.w;
            float yr = wv + Dv * xs;
            float zv = zRow[l4 + n];
            yRow[l4 + n] = yr * (zv / (1.f + __expf(-zv)));
        }
    }
}

// ---------------------------------------------------------------------------
// Classifier on last token (y is already gated).
__global__ void k_cls(const float* __restrict__ y,
                      const float* __restrict__ fcw,  // (4,48)
                      const float* __restrict__ fcb,  // (4)
                      float* __restrict__ out)
{
    int t = threadIdx.x;
    if (t >= B_ * NCLASSES) return;
    int b = t / NCLASSES;
    int c = t - b * NCLASSES;
    const float* yp = y + (size_t)b * ED * L_ + (L_ - 1);
    const float* wp = fcw + c * ED;
    float acc = fcb[c];
#pragma unroll
    for (int e = 0; e < ED; ++e) acc += yp[(size_t)e * L_] * wp[e];
    out[t] = acc;
}

// ---------------------------------------------------------------------------
extern "C" void kernel_launch(void* const* d_in, const int* in_sizes, int n_in,
                              void* d_out, int out_size, void* d_ws, size_t ws_size,
                              hipStream_t stream)
{
    const float* x          = (const float*)d_in[0];
    const float* in_proj_w  = (const float*)d_in[1];
    const float* conv_w     = (const float*)d_in[2];
    const float* conv_b     = (const float*)d_in[3];
    const float* x_proj_w   = (const float*)d_in[4];
    const float* dt_proj_w  = (const float*)d_in[5];
    const float* dt_proj_b  = (const float*)d_in[6];
    const float* A_log      = (const float*)d_in[7];
    const float* Dp         = (const float*)d_in[8];
    const float* out_proj_w = (const float*)d_in[9];
    const float* norm_w     = (const float*)d_in[10];
    const float* fc_w       = (const float*)d_in[11];
    const float* fc_b       = (const float*)d_in[12];

    float* ws   = (float*)d_ws;
    float* z    = ws;                         // B*48*L = 786432
    float* xc   = z    + B_ * ED * L_;        // 786432
    float* delta= xc   + B_ * ED * L_;        // 786432
    float* y    = delta+ B_ * ED * L_;        // 786432
    float* Bmat = y    + B_ * ED * L_;        // B*L*32 = 524288
    float* Cmat = Bmat + B_ * L_ * NS;        // 524288
    float* hA   = Cmat + B_ * L_ * NS;        // B*6*L = 98304
    float* hB   = hA   + B_ * DM * L_;        // 98304
    float* sumA = hB   + B_ * DM * L_;        // B*ED*CH*NS = 393216
    float* sumH = sumA + B_ * ED * CH * NS;   // 393216
    // total ~5.0M floats = 20 MB

    const int nScanT = B_ * ED * CH * NS;     // 393216

    for (int i = 0; i < NLAYERS; ++i) {
        float* hout      = (i & 1) ? hB : hA;
        const float* hin = (i == 0) ? nullptr : ((i & 1) ? hA : hB);
        const float* ow  = (i == 0) ? out_proj_w : out_proj_w + (size_t)(i - 1) * DM * ED;
        k_fused_pre<<<B_ * (L_ / 32), 256, 0, stream>>>(
            x, y, ow, hin, hout,
            in_proj_w + (size_t)i * 96 * DM, norm_w + (size_t)i * DM,
            conv_w + (size_t)i * ED * DCONV, conv_b + (size_t)i * ED,
            x_proj_w + (size_t)i * 65 * ED,
            dt_proj_w + (size_t)i * ED, dt_proj_b + (size_t)i * ED,
            z, xc, delta, Bmat, Cmat, i);
        k_scan1<<<(nScanT + 255) / 256, 256, 0, stream>>>(
            delta, xc, Bmat, A_log + (size_t)i * ED * NS, sumA, sumH);
        k_scan3<<<(nScanT + 255) / 256, 256, 0, stream>>>(
            delta, xc, Bmat, Cmat, z,
            A_log + (size_t)i * ED * NS, Dp + (size_t)i * ED, sumA, sumH, y);
    }
    k_cls<<<1, 64, 0, stream>>>(y, fc_w, fc_b, (float*)d_out);
}